// Round 4
// baseline (231.638 us; speedup 1.0000x reference)
//
#include <hip/hip_runtime.h>

// CAPBlock r4: NC=16 (4 blocks/CU attn), pure-fp16 swizzled-LDS MFMA GEMMs for
// the bag projections, alpha-folded exp2 softmax.
// Shapes: B=4, Q=256, K=4096, Ein=E=512, H=8, DH=64.
//
// ws (52.43MB <= proven >=52.95MB):
//   mflag 16B | qh 1MB | kh 16.8MB | vT 16.8MB | REGION 17.8MB
//   REGION phase1: bag_h 16.8 | wqk_h 0.5 | wv_h 0.5   (convert -> GEMMs)
//   REGION phase2: po 16.8 | ps 0.5                     (attn -> combine)

#define BATCH 4
#define QLEN 256
#define KLEN 4096
#define EDIM 512
#define NHEAD 8
#define DHEAD 64
#define NC 16  // k-chunks for attention partials

// alpha = log2(e)/L1_SCALING ; C2 = L1_CENTER*alpha  (k,q prescaled by alpha)
#define ALPHA 0.21153831f
#define C2EXP 15.276518f

typedef float f32x4 __attribute__((ext_vector_type(4)));
typedef _Float16 f16x8 __attribute__((ext_vector_type(8)));
typedef _Float16 f16x4 __attribute__((ext_vector_type(4)));
typedef _Float16 h2 __attribute__((ext_vector_type(2)));
typedef unsigned int u32x4 __attribute__((ext_vector_type(4)));

// ---------------- mask dtype detection (bool-as-byte vs int32) --------------
__global__ void detect_mask_kernel(const unsigned char* __restrict__ m,
                                   int* __restrict__ flag) {
    __shared__ int nz;
    if (threadIdx.x == 0) nz = 0;
    __syncthreads();
    int acc = 0;
    for (int i = threadIdx.x; i < BATCH * KLEN; i += 256)
        if (i & 3) acc |= m[i];
    if (acc) atomicOr(&nz, 1);
    __syncthreads();
    if (threadIdx.x == 0) *flag = (nz == 0) ? 1 : 0;  // 1 => int32, 0 => byte
}

// ---------------- f32 -> fp16 convert (bag, Wqk, Wv) ------------------------
__global__ __launch_bounds__(256) void convert_kernel(
    const float* __restrict__ bag, const float* __restrict__ wqk,
    const float* __restrict__ wv, _Float16* __restrict__ bag_h,
    _Float16* __restrict__ wqk_h, _Float16* __restrict__ wv_h) {
    const int NB = (BATCH * KLEN * EDIM) / 4;  // float4 counts
    const int NW = (EDIM * EDIM) / 4;
    for (int i = blockIdx.x * 256 + threadIdx.x; i < NB + 2 * NW;
         i += gridDim.x * 256) {
        const float4* s;
        _Float16* d;
        int j;
        if (i < NB) { s = (const float4*)bag; d = bag_h; j = i; }
        else if (i < NB + NW) { s = (const float4*)wqk; d = wqk_h; j = i - NB; }
        else { s = (const float4*)wv; d = wv_h; j = i - NB - NW; }
        const float4 v = s[j];
        f16x4 h;
        h[0] = (_Float16)v.x; h[1] = (_Float16)v.y;
        h[2] = (_Float16)v.z; h[3] = (_Float16)v.w;
        *(f16x4*)&d[(size_t)j * 4] = h;
    }
}

// ---------------- pure-fp16 NT MFMA GEMM (bag projections) ------------------
// C[m][n] = sum_k A[m][k]*W[n][k]; 128x128 tile, BK=64, 4 waves (2x2).
// LDS XOR-swizzle: 16B unit u of row r stored at u^(r&7) -> both the staging
// writes and the fragment reads hit each 16B unit with 8 lanes at distinct
// rows = the 1KB/wave floor (no excess conflicts).
// OUTM=0: fp16 row-major, (acc+bias[n])*scale[n]*smul.
// OUTM=1: vT[(b*8+h)*64+d][k] fp16, acc+bias[n].
template <int OUTM>
__global__ __launch_bounds__(256) void gemm_h16_mfma(
    const _Float16* __restrict__ A, const _Float16* __restrict__ W,
    const float* __restrict__ bias, const float* __restrict__ scale,
    float smul, _Float16* __restrict__ C) {
    __shared__ _Float16 Ah[128][64];
    __shared__ _Float16 Bh[128][64];

    const int tid = threadIdx.x;
    const int lane = tid & 63, wid = tid >> 6;
    const int wm = wid >> 1, wn = wid & 1;
    const int l15 = lane & 15, kg4 = lane >> 4;
    const int n0 = blockIdx.x * 128, m0 = blockIdx.y * 128;

    f32x4 acc[4][4];
#pragma unroll
    for (int i = 0; i < 4; ++i)
#pragma unroll
        for (int j = 0; j < 4; ++j) acc[i][j] = (f32x4)0.f;

    for (int k0 = 0; k0 < EDIM; k0 += 64) {
        f16x8 av[4], wv[4];
        int rowv[4], uv[4];
#pragma unroll
        for (int i = 0; i < 4; ++i) {  // lane-contiguous 16B: coalesced 1KB/wave
            const int idx = i * 256 + tid;
            rowv[i] = idx >> 3;
            uv[i] = idx & 7;
            av[i] = *(const f16x8*)&A[(size_t)(m0 + rowv[i]) * EDIM + k0 + uv[i] * 8];
            wv[i] = *(const f16x8*)&W[(size_t)(n0 + rowv[i]) * EDIM + k0 + uv[i] * 8];
        }
        __syncthreads();  // previous tile consumed
#pragma unroll
        for (int i = 0; i < 4; ++i) {
            const int sw = (uv[i] ^ (rowv[i] & 7)) * 8;
            *(f16x8*)&Ah[rowv[i]][sw] = av[i];
            *(f16x8*)&Bh[rowv[i]][sw] = wv[i];
        }
        __syncthreads();

#pragma unroll
        for (int s = 0; s < 2; ++s) {
            f16x8 a8[4], b8[4];
#pragma unroll
            for (int mf = 0; mf < 4; ++mf) {
                const int row = wm * 64 + mf * 16 + l15;
                a8[mf] = *(const f16x8*)&Ah[row][((s * 4 + kg4) ^ (row & 7)) * 8];
            }
#pragma unroll
            for (int nf = 0; nf < 4; ++nf) {
                const int row = wn * 64 + nf * 16 + l15;
                b8[nf] = *(const f16x8*)&Bh[row][((s * 4 + kg4) ^ (row & 7)) * 8];
            }
#pragma unroll
            for (int nf = 0; nf < 4; ++nf)
#pragma unroll
                for (int mf = 0; mf < 4; ++mf)
                    acc[mf][nf] = __builtin_amdgcn_mfma_f32_16x16x32_f16(
                        a8[mf], b8[nf], acc[mf][nf], 0, 0, 0);
        }
    }

#pragma unroll
    for (int nf = 0; nf < 4; ++nf) {
        const int n = n0 + wn * 64 + nf * 16 + l15;
        const float bi = bias[n];
        if constexpr (OUTM == 0) {
            const float sc = (scale ? scale[n] : 1.f) * smul;
#pragma unroll
            for (int mf = 0; mf < 4; ++mf)
#pragma unroll
                for (int rr = 0; rr < 4; ++rr) {
                    const int m = m0 + wm * 64 + mf * 16 + kg4 * 4 + rr;
                    C[(size_t)m * EDIM + n] = (_Float16)((acc[mf][nf][rr] + bi) * sc);
                }
        } else {
#pragma unroll
            for (int mf = 0; mf < 4; ++mf) {
                const int kb = m0 + wm * 64 + mf * 16 + kg4 * 4;  // global m
                const int bb = kb >> 12, kk = kb & (KLEN - 1);    // batch, k
                f16x4 pk;
#pragma unroll
                for (int rr = 0; rr < 4; ++rr) pk[rr] = (_Float16)(acc[mf][nf][rr] + bi);
                *(f16x4*)&C[((size_t)(bb * NHEAD + (n >> 6)) * DHEAD + (n & 63)) * KLEN + kk] = pk;
            }
        }
    }
}

// ---------------- mixed f32->fp16 MFMA GEMM (query projection, small) -------
__global__ __launch_bounds__(256) void gemm_f16_mfma(
    const float* __restrict__ A, const float* __restrict__ W,
    const float* __restrict__ bias, const float* __restrict__ scale,
    float smul, _Float16* __restrict__ C) {
    __shared__ _Float16 As[128][40];
    __shared__ _Float16 Bs[128][40];

    const int tid = threadIdx.x;
    const int lane = tid & 63, wid = tid >> 6;
    const int wm = wid >> 1, wn = wid & 1;
    const int l15 = lane & 15, kg4 = lane >> 4;
    const int n0 = blockIdx.x * 128, m0 = blockIdx.y * 128;

    f32x4 acc[4][4];
#pragma unroll
    for (int i = 0; i < 4; ++i)
#pragma unroll
        for (int j = 0; j < 4; ++j) acc[i][j] = (f32x4)0.f;

    const int r = tid >> 1, hk = tid & 1;

    for (int k0 = 0; k0 < EDIM; k0 += 32) {
        float4 av[4], wv[4];
#pragma unroll
        for (int i = 0; i < 4; ++i) {
            av[i] = *(const float4*)&A[(size_t)(m0 + r) * EDIM + k0 + hk * 16 + i * 4];
            wv[i] = *(const float4*)&W[(size_t)(n0 + r) * EDIM + k0 + hk * 16 + i * 4];
        }
        __syncthreads();
        f16x8 ha0, ha1, hb0, hb1;
#pragma unroll
        for (int i = 0; i < 4; ++i) {
            const float* af = (const float*)&av[i];
            const float* wf = (const float*)&wv[i];
            if (i < 2) {
#pragma unroll
                for (int j = 0; j < 4; ++j) { ha0[i * 4 + j] = (_Float16)af[j]; hb0[i * 4 + j] = (_Float16)wf[j]; }
            } else {
#pragma unroll
                for (int j = 0; j < 4; ++j) { ha1[(i - 2) * 4 + j] = (_Float16)af[j]; hb1[(i - 2) * 4 + j] = (_Float16)wf[j]; }
            }
        }
        *(f16x8*)&As[r][hk * 16] = ha0;
        *(f16x8*)&As[r][hk * 16 + 8] = ha1;
        *(f16x8*)&Bs[r][hk * 16] = hb0;
        *(f16x8*)&Bs[r][hk * 16 + 8] = hb1;
        __syncthreads();

        f16x8 a8[4];
#pragma unroll
        for (int mf = 0; mf < 4; ++mf)
            a8[mf] = *(const f16x8*)&As[wm * 64 + mf * 16 + l15][kg4 * 8];
#pragma unroll
        for (int nf = 0; nf < 4; ++nf) {
            const f16x8 b8 = *(const f16x8*)&Bs[wn * 64 + nf * 16 + l15][kg4 * 8];
#pragma unroll
            for (int mf = 0; mf < 4; ++mf)
                acc[mf][nf] = __builtin_amdgcn_mfma_f32_16x16x32_f16(a8[mf], b8, acc[mf][nf], 0, 0, 0);
        }
    }

#pragma unroll
    for (int nf = 0; nf < 4; ++nf) {
        const int n = n0 + wn * 64 + nf * 16 + l15;
        const float bi = bias[n];
        const float sc = (scale ? scale[n] : 1.f) * smul;
#pragma unroll
        for (int mf = 0; mf < 4; ++mf)
#pragma unroll
            for (int rr = 0; rr < 4; ++rr) {
                const int m = m0 + wm * 64 + mf * 16 + kg4 * 4 + rr;
                C[(size_t)m * EDIM + n] = (_Float16)((acc[mf][nf][rr] + bi) * sc);
            }
    }
}

// ---------------- L1-distance attention, MFMA PV ----------------------------
// grid (NC*2, H, B) = 1024 blocks (4/CU); block = 4 waves x 32 q, chunk 256 k.
__device__ __forceinline__ float l1acc(unsigned ku, unsigned qu, float acc) {
    const h2 d = __builtin_bit_cast(h2, ku) - __builtin_bit_cast(h2, qu);
    const unsigned du = __builtin_bit_cast(unsigned, d) & 0x7fff7fffu;
    const h2 one2 = {(_Float16)1.f, (_Float16)1.f};
    return __builtin_amdgcn_fdot2(__builtin_bit_cast(h2, du), one2, acc, false);
}

__global__ __launch_bounds__(256) void attn_mfma_kernel(
    const _Float16* __restrict__ qh, const _Float16* __restrict__ kh,
    const _Float16* __restrict__ vT, const void* __restrict__ mask,
    const float* __restrict__ rel, const int* __restrict__ mflag,
    unsigned short* __restrict__ po, float* __restrict__ ps) {
    __shared__ union SM {
        struct { _Float16 K[64][64]; _Float16 V[64][72]; _Float16 M[64]; } t;
        _Float16 osm[64][136];  // epilogue d x q transpose buffer
    } sm;

    const int tid = threadIdx.x;
    const int lane = tid & 63, wid = tid >> 6;
    const int l15 = lane & 15, kg4 = lane >> 4;
    const int c = blockIdx.x & (NC - 1), qhi = blockIdx.x / NC;
    const int h = blockIdx.y, b = blockIdx.z;
    const int qbase = qhi * 128 + wid * 32;
    const int mfl = *mflag;
    const float adn = rel[b * NHEAD + h];

    unsigned qreg[2][32];
#pragma unroll
    for (int s = 0; s < 2; ++s) {
        const int qrow = b * QLEN + qbase + s * 16 + l15;
#pragma unroll
        for (int c8 = 0; c8 < 8; ++c8) {
            const f16x8 v = *(const f16x8*)&qh[(size_t)qrow * EDIM + h * DHEAD + c8 * 8];
            const u32x4 u = __builtin_bit_cast(u32x4, v);
#pragma unroll
            for (int p = 0; p < 4; ++p) qreg[s][c8 * 4 + p] = u[p];
        }
    }

    f32x4 acc[2][4];
#pragma unroll
    for (int s = 0; s < 2; ++s)
#pragma unroll
        for (int nf = 0; nf < 4; ++nf) acc[s][nf] = (f32x4)0.f;
    float sacc[2] = {0.f, 0.f};

    const int kc0 = c * (KLEN / NC);
    for (int t = 0; t < (KLEN / NC) / 64; ++t) {
        const int kbase = kc0 + t * 64;
        __syncthreads();  // previous tile consumed
        {
            const int rr = tid >> 2, c0 = (tid & 3) * 2;
            const f16x8* gk = (const f16x8*)&kh[((size_t)(b * KLEN + kbase + rr)) * EDIM + h * DHEAD + c0 * 8];
            const int sw = (rr >> 3) & 7;
            *(f16x8*)&sm.t.K[rr][((c0) ^ sw) * 8] = gk[0];
            *(f16x8*)&sm.t.K[rr][((c0 + 1) ^ sw) * 8] = gk[1];
            const f16x8* gv = (const f16x8*)&vT[((size_t)((b * NHEAD + h) * DHEAD + rr)) * KLEN + kbase + c0 * 8];
            *(f16x8*)&sm.t.V[rr][c0 * 8] = gv[0];
            *(f16x8*)&sm.t.V[rr][c0 * 8 + 8] = gv[1];
            if (tid < 64) {
                const int kg = b * KLEN + kbase + tid;
                const int mv = mfl ? ((const int*)mask)[kg]
                                   : (int)((const unsigned char*)mask)[kg];
                sm.t.M[tid] = mv ? (_Float16)1.f : (_Float16)0.f;
            }
        }
        __syncthreads();

#pragma unroll
        for (int hf = 0; hf < 2; ++hf) {
            const int kl0 = hf * 32 + kg4 * 8;
            float dist[2][8];
#pragma unroll
            for (int s = 0; s < 2; ++s)
#pragma unroll
                for (int j = 0; j < 8; ++j) dist[s][j] = 0.f;

#pragma unroll
            for (int j = 0; j < 8; ++j) {
                const int kk = kl0 + j;
                const int sw = (kk >> 3) & 7;
#pragma unroll
                for (int c8 = 0; c8 < 8; ++c8) {
                    const f16x8 kv = *(const f16x8*)&sm.t.K[kk][(c8 ^ sw) * 8];
                    const u32x4 ku = __builtin_bit_cast(u32x4, kv);
#pragma unroll
                    for (int p = 0; p < 4; ++p) {
                        dist[0][j] = l1acc(ku[p], qreg[0][c8 * 4 + p], dist[0][j]);
                        dist[1][j] = l1acc(ku[p], qreg[1][c8 * 4 + p], dist[1][j]);
                    }
                }
            }

            const f16x8 mv8 = *(const f16x8*)&sm.t.M[kl0];
            unsigned pw[2][4];
#pragma unroll
            for (int s = 0; s < 2; ++s) {
                float w[8];
#pragma unroll
                for (int j = 0; j < 8; ++j) {
                    // e = mask * 2^(C2 - dist); w = e/(e+adn)  (== reference)
                    const float e = exp2f(C2EXP - dist[s][j]) * (float)mv8[j];
                    w[j] = e * __builtin_amdgcn_rcpf(e + adn);
                    sacc[s] += w[j];
                }
#pragma unroll
                for (int m2 = 0; m2 < 4; ++m2)
                    pw[s][m2] = __builtin_bit_cast(unsigned,
                        __builtin_amdgcn_cvt_pkrtz(w[2 * m2], w[2 * m2 + 1]));
            }

#pragma unroll
            for (int nf = 0; nf < 4; ++nf) {
                const f16x8 b8 = *(const f16x8*)&sm.t.V[nf * 16 + l15][hf * 32 + kg4 * 8];
                union { unsigned u[4]; f16x8 v; } a0, a1;
#pragma unroll
                for (int p = 0; p < 4; ++p) { a0.u[p] = pw[0][p]; a1.u[p] = pw[1][p]; }
                acc[0][nf] = __builtin_amdgcn_mfma_f32_16x16x32_f16(a0.v, b8, acc[0][nf], 0, 0, 0);
                acc[1][nf] = __builtin_amdgcn_mfma_f32_16x16x32_f16(a1.v, b8, acc[1][nf], 0, 0, 0);
            }
        }
    }

#pragma unroll
    for (int s = 0; s < 2; ++s) {
        sacc[s] += __shfl_xor(sacc[s], 16);
        sacc[s] += __shfl_xor(sacc[s], 32);
    }
    const size_t bhc = (size_t)(b * NHEAD + h) * NC + c;
    if (lane < 16) {
#pragma unroll
        for (int s = 0; s < 2; ++s)
            ps[bhc * QLEN + qbase + s * 16 + lane] = sacc[s];
    }

    __syncthreads();  // everyone done with sm.t
#pragma unroll
    for (int s = 0; s < 2; ++s)
#pragma unroll
        for (int nf = 0; nf < 4; ++nf)
#pragma unroll
            for (int rr = 0; rr < 4; ++rr) {
                const int qloc = wid * 32 + s * 16 + kg4 * 4 + rr;
                sm.osm[nf * 16 + l15][qloc] = (_Float16)acc[s][nf][rr];
            }
    __syncthreads();
    {
        const int d = tid >> 2, seg = tid & 3;
        const f16x8* src = (const f16x8*)&sm.osm[d][seg * 32];
        f16x8* dst = (f16x8*)(po + (bhc * 64 + d) * QLEN + qhi * 128 + seg * 32);
#pragma unroll
        for (int i = 0; i < 4; ++i) dst[i] = src[i];
    }
}

// ---------------- combine partials, normalize, write out --------------------
__global__ __launch_bounds__(256) void combine_kernel(
    const unsigned short* __restrict__ po, const float* __restrict__ ps,
    float* __restrict__ out, int nch) {
    const int d4 = blockIdx.x, h = blockIdx.y, b = blockIdx.z;
    const int q = threadIdx.x;
    const int bh = b * NHEAD + h;

    float s = 0.f;
    for (int c = 0; c < nch; ++c)
        s += ps[((size_t)(bh * nch + c)) * QLEN + q];

    float o[4] = {0.f, 0.f, 0.f, 0.f};
    for (int c = 0; c < nch; ++c) {
#pragma unroll
        for (int j = 0; j < 4; ++j) {
            const int d = d4 * 4 + j;
            const unsigned short raw = po[((size_t)((bh * nch + c) * 64 + d)) * QLEN + q];
            o[j] += (float)*(const _Float16*)&raw;
        }
    }
    const float inv = 1.0f / fmaxf(s, 1e-12f);
#pragma unroll
    for (int j = 0; j < 4; ++j)
        out[((size_t)(b * QLEN + q)) * EDIM + h * DHEAD + d4 * 4 + j] = o[j] * inv;
}

extern "C" void kernel_launch(void* const* d_in, const int* in_sizes, int n_in,
                              void* d_out, int out_size, void* d_ws, size_t ws_size,
                              hipStream_t stream) {
    const float* query = (const float*)d_in[0];
    const float* bag   = (const float*)d_in[1];
    const void*  mask  = d_in[2];
    const float* rel   = (const float*)d_in[3];
    const float* Wqk   = (const float*)d_in[4];
    const float* bqk   = (const float*)d_in[5];
    const float* Wv    = (const float*)d_in[6];
    const float* bv    = (const float*)d_in[7];
    const float* diag  = (const float*)d_in[8];  // [H*DH] == q/k column order
    float* out = (float*)d_out;

    char* wsb = (char*)d_ws;
    int* mflag = (int*)wsb;
    _Float16* qh = (_Float16*)(wsb + 16);
    _Float16* kh = qh + (size_t)BATCH * QLEN * EDIM;
    _Float16* vT = kh + (size_t)BATCH * KLEN * EDIM;
    char* region = (char*)(vT + (size_t)BATCH * KLEN * EDIM);
    // phase 1 (pre-attn)
    _Float16* bag_h = (_Float16*)region;
    _Float16* wqk_h = bag_h + (size_t)BATCH * KLEN * EDIM;
    _Float16* wv_h = wqk_h + (size_t)EDIM * EDIM;
    // phase 2 (attn output partials) — overlaps phase 1 (order-safe)
    unsigned short* po = (unsigned short*)region;
    float* psb = (float*)(region + (size_t)BATCH * NHEAD * NC * QLEN * DHEAD * 2);

    detect_mask_kernel<<<1, 256, 0, stream>>>((const unsigned char*)mask, mflag);

    convert_kernel<<<2048, 256, 0, stream>>>(bag, Wqk, Wv, bag_h, wqk_h, wv_h);

    // q' = (query@Wqk^T + bqk) * diag * alpha  (mixed path, small)
    gemm_f16_mfma<<<dim3(EDIM / 128, (BATCH * QLEN) / 128), 256, 0, stream>>>(
        query, Wqk, bqk, diag, ALPHA, qh);
    // k' = (bag@Wqk^T + bqk) * diag * alpha
    gemm_h16_mfma<0><<<dim3(EDIM / 128, (BATCH * KLEN) / 128), 256, 0, stream>>>(
        bag_h, wqk_h, bqk, diag, ALPHA, kh);
    // v = bag@Wv^T + bv  -> transposed vT
    gemm_h16_mfma<1><<<dim3(EDIM / 128, (BATCH * KLEN) / 128), 256, 0, stream>>>(
        bag_h, wv_h, bv, nullptr, 1.f, vT);

    attn_mfma_kernel<<<dim3(NC * 2, NHEAD, BATCH), 256, 0, stream>>>(
        qh, kh, vT, mask, rel, mflag, po, psb);

    combine_kernel<<<dim3(16, NHEAD, BATCH), 256, 0, stream>>>(po, psb, out, NC);
}